// Round 16
// baseline (30456.403 us; speedup 1.0000x reference)
//
#include <hip/hip_runtime.h>
#include <math.h>

#define TT 256
#define BB 32
#define DD 512
#define HH 512
#define H3 1536

static constexpr size_t SZ_I2HT = 3ull * H3 * HH;
static constexpr size_t SZ_H2HT = 3ull * H3 * HH;
static constexpr size_t SZ_WCT  = 3ull * HH * HH;
static constexpr size_t SZ_WGT  = 9ull * HH * HH;
static constexpr size_t SZ_UGT  = 9ull * HH * H3;
static constexpr size_t SZ_UCT  = 9ull * HH * HH;
static constexpr size_t SZ_ST   = 3ull * BB * HH;
static constexpr size_t SZ_GH   = 3ull * BB * H3;
static constexpr size_t SZ_UGP  = 3ull * 9 * BB * HH;  // partials [chunk][q][b][col]
static constexpr size_t SZ_UCB  = 9ull * BB * HH;

static constexpr size_t OFF_I2HT = 0;
static constexpr size_t OFF_H2HT = OFF_I2HT + SZ_I2HT;
static constexpr size_t OFF_WCT  = OFF_H2HT + SZ_H2HT;
static constexpr size_t OFF_WGT  = OFF_WCT + SZ_WCT;
static constexpr size_t OFF_UGT  = OFF_WGT + SZ_WGT;
static constexpr size_t OFF_UCT  = OFF_UGT + SZ_UGT;
static constexpr size_t OFF_HST  = OFF_UCT + SZ_UCT;
static constexpr size_t OFF_CST  = OFF_HST + SZ_ST;
static constexpr size_t OFF_GH   = OFF_CST + SZ_ST;
static constexpr size_t OFF_UGP  = OFF_GH + SZ_GH;
static constexpr size_t OFF_UCB  = OFF_UGP + SZ_UGP;
static constexpr size_t WS_FLOATS = OFF_UCB + SZ_UCB;
// pipelined mode appends a second ugp/ucb buffer (t-parity double buffer)
static constexpr size_t OFF_UGP2 = OFF_UCB + SZ_UCB;
static constexpr size_t OFF_UCB2 = OFF_UGP2 + SZ_UGP;
static constexpr size_t WS_FLOATS2 = OFF_UCB2 + SZ_UCB;

struct KArgs {
  const float* x;
  const float *b_i2h, *b_h2h, *b_wg, *b_ug, *b_uc, *b_wc;
  const float *i2hT, *h2hT, *wcT, *wgT, *ugT, *ucT;
  float *hst, *cst, *gh, *ugp, *ucb, *ugp2, *ucb2, *out;
};

// ---------------- cross-XCD coherent access helpers (sc1 path, no cache flushes)
__device__ __forceinline__ float cload(const float* p) {
  return __hip_atomic_load(p, __ATOMIC_RELAXED, __HIP_MEMORY_SCOPE_AGENT);
}
__device__ __forceinline__ void cstore(float* p, float v) {
  __hip_atomic_store(p, v, __ATOMIC_RELAXED, __HIP_MEMORY_SCOPE_AGENT);
}
__device__ __forceinline__ void cstore2(float* p, float2 v) {
  __hip_atomic_store(reinterpret_cast<unsigned long long*>(p),
                     __builtin_bit_cast(unsigned long long, v),
                     __ATOMIC_RELAXED, __HIP_MEMORY_SCOPE_AGENT);
}

// ---------------- sync: TWO 64-sharded monotonic counter arrays (A-arrivals,
// B-arrivals), wave-parallel direct poll-sum (r13/r15-validated semantics:
// every waiter directly observes every arrival line; no mediated release).
__device__ unsigned int g_cntA[64 * 64];
__device__ unsigned int g_cntB[64 * 64];

__global__ void k_zero() {
  for (int i = threadIdx.x; i < 64 * 64; i += blockDim.x) {
    g_cntA[i] = 0u;
    g_cntB[i] = 0u;
  }
}

__device__ __forceinline__ void arrive(unsigned int* cnt) {
  __syncthreads();  // drains vmcnt: all sc1 stores at coherence point pre-RMW
  if (threadIdx.x == 0) {
    __hip_atomic_fetch_add(&cnt[(blockIdx.x & 63) * 64], 1u,
                           __ATOMIC_RELAXED, __HIP_MEMORY_SCOPE_AGENT);
  }
}

__device__ __forceinline__ void wait_for(unsigned int* cnt, unsigned int target) {
  if (threadIdx.x < 64) {
    for (;;) {
      unsigned int s = __hip_atomic_load(&cnt[threadIdx.x * 64],
                                         __ATOMIC_RELAXED, __HIP_MEMORY_SCOPE_AGENT);
      s += __shfl_xor(s, 1);
      s += __shfl_xor(s, 2);
      s += __shfl_xor(s, 4);
      s += __shfl_xor(s, 8);
      s += __shfl_xor(s, 16);
      s += __shfl_xor(s, 32);
      if (s >= target) break;
      __builtin_amdgcn_s_sleep(8);
    }
  }
  __syncthreads();
}

// ---------------- transpose: in [K][N] -> out [N][K], grid (N/32, K/32, nmat)
__global__ __launch_bounds__(256) void k_transpose(const float* __restrict__ in,
                                                   float* __restrict__ out,
                                                   int K, int N) {
  __shared__ float t[32][33];
  size_t mo = (size_t)blockIdx.z * K * N;
  in += mo; out += mo;
  int n0 = blockIdx.x * 32, k0 = blockIdx.y * 32;
  int c = threadIdx.x & 31, r0 = (threadIdx.x >> 5) * 4;
#pragma unroll
  for (int i = 0; i < 4; ++i) t[r0 + i][c] = in[(size_t)(k0 + r0 + i) * N + n0 + c];
  __syncthreads();
#pragma unroll
  for (int i = 0; i < 4; ++i) out[(size_t)(n0 + r0 + i) * K + k0 + c] = t[c][r0 + i];
}

__global__ void k_copy(const float* __restrict__ a, float* __restrict__ o, int n) {
  int i = blockIdx.x * blockDim.x + threadIdx.x;
  if (i < n) o[i] = a[i];
}

// k-aware XOR swizzle: granule g (16B) of a row stored at slot g^((g>>4)&7).
__device__ __forceinline__ int xslot(int g) { return g ^ ((g >> 4) & 7); }

__device__ __forceinline__ void stage_swz(const float* __restrict__ src,
                                          float* __restrict__ sx, int tid) {
#pragma unroll 8
  for (int fi = tid; fi < (BB * HH) / 4; fi += 256) {
    int b = fi >> 7, g = fi & 127;
    float4 v = reinterpret_cast<const float4*>(src)[fi];
    *reinterpret_cast<float4*>(&sx[b * HH + (xslot(g) << 2)]) = v;
  }
}

// 16B sc1 coherent staging (r14-validated): batches of 8 loads in flight,
// one vmcnt(0) drain, then LDS writes.
__device__ __forceinline__ void stage_swz_coh(const float* __restrict__ src,
                                              float* __restrict__ sx, int tid) {
#pragma unroll
  for (int half = 0; half < 2; ++half) {
    float4 v[8];
#pragma unroll
    for (int i = 0; i < 8; ++i) {
      int fi = tid + (half * 8 + i) * 256;
      const float* p = src + (size_t)fi * 4;
      asm volatile("global_load_dwordx4 %0, %1, off sc1" : "=v"(v[i]) : "v"(p));
    }
    asm volatile("s_waitcnt vmcnt(0)" ::: "memory");
#pragma unroll
    for (int i = 0; i < 8; ++i) {
      int fi = tid + (half * 8 + i) * 256;
      int b = fi >> 7, g = fi & 127;
      *reinterpret_cast<float4*>(&sx[b * HH + (xslot(g) << 2)]) = v[i];
    }
  }
}

// 16-row parity-half stage (nopipe phase A)
__device__ __forceinline__ void stage_half_coh(const float* __restrict__ src,
                                               float* __restrict__ sx, int tid) {
  float4 v[8];
#pragma unroll
  for (int i = 0; i < 8; ++i) {
    int fi = tid + i * 256;
    const float* p = src + (size_t)fi * 4;
    asm volatile("global_load_dwordx4 %0, %1, off sc1" : "=v"(v[i]) : "v"(p));
  }
  asm volatile("s_waitcnt vmcnt(0)" ::: "memory");
#pragma unroll
  for (int i = 0; i < 8; ++i) {
    int fi = tid + i * 256;
    int b = fi >> 7, g = fi & 127;
    *reinterpret_cast<float4*>(&sx[b * HH + (xslot(g) << 2)]) = v[i];
  }
}

__device__ __forceinline__ float dot4(float4 x, float4 w) {
  return x.x * w.x + x.y * w.y + x.z * w.z + x.w * w.w;
}

__device__ __forceinline__ float sigm(float x) { return 1.0f / (1.0f + expf(-x)); }

// ---------------- phase A unit (r13-validated bh-decode; full 32-row sx).
// One wave computes one unit: 32 cols x 16 b (bh = b-half).
__device__ __forceinline__ void phaseA_unit(const KArgs& A, const float* sx,
                                            float* scr, int wid, int lane,
                                            int src, int u,
                                            float* ugp_buf, float* ucb_buf) {
  const int cq = lane & 7, kc = lane >> 3;
  const float* wb; size_t wstride; size_t koff = 0;
  float* op; int opstride;
  const float* bias1 = nullptr; const float* bias2 = nullptr;
  int col0, bh;
  if (u < 96) {  // gh (h2h for layer src)
    int w = u >> 1; bh = u & 1; col0 = w * 32;
    wb = A.h2hT + (size_t)src * H3 * HH; wstride = HH;
    op = A.gh + (size_t)src * BB * H3; opstride = H3;
    bias1 = A.b_i2h + src * H3; bias2 = A.b_h2h + src * H3;
  } else if (u < 384) {  // ugp partial, chunk = src
    int v = u - 96; int w = v >> 1; bh = v & 1;
    int q = w >> 4; col0 = (w & 15) * 32;
    wb = A.ugT + (size_t)q * HH * H3; wstride = H3; koff = (size_t)src * HH;
    op = ugp_buf + (size_t)(src * 9 + q) * BB * HH; opstride = HH;
    if (src == 0) { bias1 = A.b_wg + q * HH; bias2 = A.b_ug + q * HH; }
  } else {  // ucb, q = qi*3 + src
    int v = u - 384; int w = v >> 1; bh = v & 1;
    int qi = w >> 4; int q = qi * 3 + src; col0 = (w & 15) * 32;
    wb = A.ucT + (size_t)q * HH * HH; wstride = HH;
    op = ucb_buf + (size_t)q * BB * HH; opstride = HH;
    bias1 = A.b_uc + q * HH;
  }

  const int cbase = col0 + cq * 4;
  const float* w0 = wb + (size_t)(cbase + 0) * wstride + koff;
  const float* w1 = wb + (size_t)(cbase + 1) * wstride + koff;
  const float* w2 = wb + (size_t)(cbase + 2) * wstride + koff;
  const float* w3 = wb + (size_t)(cbase + 3) * wstride + koff;
  const float* xb = sx + (size_t)(bh * 16) * HH;

  float acc[4][16];
#pragma unroll
  for (int c = 0; c < 4; ++c)
#pragma unroll
    for (int b = 0; b < 16; ++b) acc[c][b] = 0.f;

  for (int jt = 0; jt < 16; ++jt) {
    const int g = jt * 8 + kc;
    const int k = g << 2;
    float4 wv0 = *reinterpret_cast<const float4*>(w0 + k);
    float4 wv1 = *reinterpret_cast<const float4*>(w1 + k);
    float4 wv2 = *reinterpret_cast<const float4*>(w2 + k);
    float4 wv3 = *reinterpret_cast<const float4*>(w3 + k);
    const int so = xslot(g) << 2;
#pragma unroll
    for (int b = 0; b < 16; ++b) {
      float4 xv = *reinterpret_cast<const float4*>(&xb[b * HH + so]);
      acc[0][b] += dot4(xv, wv0);
      acc[1][b] += dot4(xv, wv1);
      acc[2][b] += dot4(xv, wv2);
      acc[3][b] += dot4(xv, wv3);
    }
  }

#pragma unroll
  for (int c = 0; c < 4; ++c)
#pragma unroll
    for (int b = 0; b < 16; ++b) {
      float v = acc[c][b];
      v += __shfl_xor(v, 8);
      v += __shfl_xor(v, 16);
      v += __shfl_xor(v, 32);
      acc[c][b] = v;
    }

  float* wscr = scr + wid * 512;
  if (kc == 0) {
#pragma unroll
    for (int c = 0; c < 4; ++c) {
#pragma unroll
      for (int b = 0; b < 16; b += 4) {
        *reinterpret_cast<float4*>(&wscr[cq * 64 + c * 16 + b]) =
            make_float4(acc[c][b], acc[c][b + 1], acc[c][b + 2], acc[c][b + 3]);
      }
    }
  }
  {
    const int bl = lane & 15;
    const int cg = lane >> 4;
    const int b = bh * 16 + bl;
    float* orow = op + (size_t)b * opstride + col0 + cg * 8;
#pragma unroll
    for (int i = 0; i < 8; i += 2) {
      int cl0 = cg * 8 + i, cl1 = cl0 + 1;
      float v0 = wscr[(cl0 >> 2) * 64 + (cl0 & 3) * 16 + bl];
      float v1 = wscr[(cl1 >> 2) * 64 + (cl1 & 3) * 16 + bl];
      int col = col0 + cl0;
      if (bias1) { v0 += bias1[col]; v1 += bias1[col + 1]; }
      if (bias2) { v0 += bias2[col]; v1 += bias2[col + 1]; }
      cstore2(orow + i, make_float2(v0, v1));
    }
  }
}

// ---------------- nopipe phase A (r15-validated parity version), 480 blocks x 3 units
__device__ __forceinline__ void phaseA_work(const KArgs& A, float* sx, float* scr,
                                            float* ugp_buf, float* ucb_buf) {
  const int tid = threadIdx.x;
  const int bid = blockIdx.x;
  const int src = bid / 160;
  const int blk = bid - src * 160;
  const int p = blk & 1;
  stage_half_coh(A.hst + ((size_t)src * BB + p * 16) * HH, sx, tid);
  __syncthreads();
  const int wid = tid >> 6;
  if (wid == 3) return;
  const int lane = tid & 63;
  const int u = (blk >> 1) * 6 + wid * 2 + p;  // u&1 == p
  // reuse unit body with a shifted sx base: parity staging put rows at sx[0..16)
  // emulate by temporarily treating bh half: unit expects xb = sx + bh*16*HH and
  // bh == p, but rows staged at offset 0 — so pass sx - p*16*HH? Instead inline:
  // call phaseA_unit with sx shifted so that bh*16*HH lands on the staged rows.
  phaseA_unit(A, sx - (size_t)(p * 16) * HH, scr, wid, lane, src, u, ugp_buf, ucb_buf);
}

// ---------------- phase B: 256 units of (8 j x 8 b), unit = bid (<256).
__device__ __forceinline__ void phaseB_work(const KArgs& A, float* sx, float* scr,
                                            int l, int t,
                                            const float* ugp_t, const float* ucb_t) {
  const int tid = threadIdx.x;
  const int bid = blockIdx.x;
  if (l == 0) stage_swz(A.x + (size_t)t * BB * DD, sx, tid);
  else        stage_swz_coh(A.hst + (size_t)(l - 1) * BB * HH, sx, tid);
  __syncthreads();
  const int jq = tid & 7;
  const int kcl = (tid >> 3) & 7;
  const int wid = tid >> 6;
  const int jg = (bid & 7) + ((bid >> 5) << 3);  // XCD-aware 4x weight dedup (r10)
  const int bq = (bid >> 3) & 3;
  const int j0 = jg * 8;
  const int j = j0 + jq;
  const float* w0 = A.i2hT + ((size_t)l * H3 + j) * HH;
  const float* w1 = A.i2hT + ((size_t)l * H3 + HH + j) * HH;
  const float* w2 = A.i2hT + ((size_t)l * H3 + 2 * HH + j) * HH;
  const float* w3 = A.wgT + ((size_t)(l * 3 + 0) * HH + j) * HH;
  const float* w4 = A.wgT + ((size_t)(l * 3 + 1) * HH + j) * HH;
  const float* w5 = A.wgT + ((size_t)(l * 3 + 2) * HH + j) * HH;
  const float* w6 = A.wcT + ((size_t)l * HH + j) * HH;
  const float* xb = sx + (size_t)(bq * 8) * HH;

  float acc[7][8];
#pragma unroll
  for (int m = 0; m < 7; ++m)
#pragma unroll
    for (int b = 0; b < 8; ++b) acc[m][b] = 0.f;

  for (int jt = 0; jt < 4; ++jt) {
    const int g = wid * 32 + jt * 8 + kcl;
    const int k = g << 2;
    float4 v0 = *reinterpret_cast<const float4*>(w0 + k);
    float4 v1 = *reinterpret_cast<const float4*>(w1 + k);
    float4 v2 = *reinterpret_cast<const float4*>(w2 + k);
    float4 v3 = *reinterpret_cast<const float4*>(w3 + k);
    float4 v4 = *reinterpret_cast<const float4*>(w4 + k);
    float4 v5 = *reinterpret_cast<const float4*>(w5 + k);
    float4 v6 = *reinterpret_cast<const float4*>(w6 + k);
    const int so = xslot(g) << 2;
#pragma unroll
    for (int b = 0; b < 8; ++b) {
      float4 xv = *reinterpret_cast<const float4*>(&xb[b * HH + so]);
      acc[0][b] += dot4(xv, v0);
      acc[1][b] += dot4(xv, v1);
      acc[2][b] += dot4(xv, v2);
      acc[3][b] += dot4(xv, v3);
      acc[4][b] += dot4(xv, v4);
      acc[5][b] += dot4(xv, v5);
      acc[6][b] += dot4(xv, v6);
    }
  }
#pragma unroll
  for (int m = 0; m < 7; ++m)
#pragma unroll
    for (int b = 0; b < 8; ++b) {
      float v = acc[m][b];
      v += __shfl_xor(v, 8);
      v += __shfl_xor(v, 16);
      v += __shfl_xor(v, 32);
      acc[m][b] = v;
    }
  if ((tid & 63) < 8) {
    float* pp = scr + wid * 448 + jq * 56;
#pragma unroll
    for (int m = 0; m < 7; ++m) {
      *reinterpret_cast<float4*>(&pp[m * 8 + 0]) =
          make_float4(acc[m][0], acc[m][1], acc[m][2], acc[m][3]);
      *reinterpret_cast<float4*>(&pp[m * 8 + 4]) =
          make_float4(acc[m][4], acc[m][5], acc[m][6], acc[m][7]);
    }
  }
  __syncthreads();
  if (tid < 64) {
    const int jr = tid & 7, br = tid >> 3;
    float a[7];
#pragma unroll
    for (int m = 0; m < 7; ++m) {
      const int o = jr * 56 + m * 8 + br;
      a[m] = scr[o] + scr[448 + o] + scr[896 + o] + scr[1344 + o];
    }
    const int jj = j0 + jr;
    const int b = bq * 8 + br;
    const size_t bh_ = (size_t)b * HH + jj;
    const float* gh_l = A.gh + (size_t)l * BB * H3;
    float si = sigm(a[0] + cload(&gh_l[(size_t)b * H3 + jj]));
    float sf = sigm(a[1] + cload(&gh_l[(size_t)b * H3 + HH + jj]));
    float so = sigm(a[2] + cload(&gh_l[(size_t)b * H3 + 2 * HH + jj]));
    const size_t CH = 9ull * BB * HH;
    size_t o0 = ((size_t)(l * 3 + 0) * BB + b) * HH + jj;
    size_t o1 = ((size_t)(l * 3 + 1) * BB + b) * HH + jj;
    size_t o2 = ((size_t)(l * 3 + 2) * BB + b) * HH + jj;
    float g0 = sigm(a[3] + cload(&ugp_t[o0]) + cload(&ugp_t[o0 + CH]) + cload(&ugp_t[o0 + 2 * CH]));
    float g1 = sigm(a[4] + cload(&ugp_t[o1]) + cload(&ugp_t[o1 + CH]) + cload(&ugp_t[o1 + 2 * CH]));
    float g2 = sigm(a[5] + cload(&ugp_t[o2]) + cload(&ugp_t[o2 + CH]) + cload(&ugp_t[o2 + 2 * CH]));
    float accc = a[6] + A.b_wc[l * HH + jj]
               + g0 * cload(&ucb_t[o0]) + g1 * cload(&ucb_t[o1]) + g2 * cload(&ucb_t[o2]);
    float cand = tanhf(accc);
    float* cp = A.cst + (size_t)l * BB * HH + bh_;
    float* hp = A.hst + (size_t)l * BB * HH + bh_;
    float cn = sf * cload(cp) + si * cand;
    float hn = so * tanhf(cn);
    cstore(cp, cn);
    cstore(hp, hn);
    if (l == 2) A.out[(size_t)t * BB * HH + bh_] = hn;
  }
}

// ---------------- PIPELINED persistent kernel: B-blocks 0..255, A-blocks 256..479.
// A(t+1) src=s runs concurrently with B(s+1..2)(t) on dedicated blocks;
// ugp/ucb double-buffered by t-parity; gh safe single-buffered (A src=s waits
// its only reader B(s)(t)). Dual counter arrays, direct-observation waits.
__global__ __launch_bounds__(256, 2) void k_persist_pipe(KArgs A) {
  __shared__ float sx[BB * HH];
  __shared__ float scr[2048];
  const int bid = blockIdx.x;
  const int tid = threadIdx.x;
  if (bid < 256) {
    for (int t = 0; t < TT; ++t) {
      wait_for(g_cntA, (unsigned)(t + 1) * 224u);          // A(t) complete
      float* ugp_t = (t & 1) ? A.ugp2 : A.ugp;
      float* ucb_t = (t & 1) ? A.ucb2 : A.ucb;
      const unsigned base = 3u * (unsigned)t * 256u;
      phaseB_work(A, sx, scr, 0, t, ugp_t, ucb_t);
      arrive(g_cntB);
      wait_for(g_cntB, base + 256u);
      phaseB_work(A, sx, scr, 1, t, ugp_t, ucb_t);
      arrive(g_cntB);
      wait_for(g_cntB, base + 512u);
      phaseB_work(A, sx, scr, 2, t, ugp_t, ucb_t);
      arrive(g_cntB);
    }
    wait_for(g_cntB, 3u * TT * 256u);
  } else {
    const int a = bid - 256;                // 0..223
    const int src = (a < 75) ? 0 : (a < 150) ? 1 : 2;
    const int i0 = a - ((src == 0) ? 0 : (src == 1) ? 75 : 150);
    const int nblk = (src < 2) ? 75 : 74;
    const int lo = (i0 * 480) / nblk;
    const int hi = ((i0 + 1) * 480) / nblk; // 6-7 units, all of this src
    const int wid = tid >> 6, lane = tid & 63;
    // prologue: A(0) from h0 into buffer 0
    stage_swz_coh(A.hst + (size_t)src * BB * HH, sx, tid);
    __syncthreads();
    for (int it = 0; lo + it * 4 < hi; ++it) {
      int u = lo + it * 4 + wid;
      if (u < hi) phaseA_unit(A, sx, scr, wid, lane, src, u, A.ugp, A.ucb);
    }
    arrive(g_cntA);
    for (int t = 0; t < TT; ++t) {
      if (t + 1 < TT) {
        wait_for(g_cntB, 3u * (unsigned)t * 256u + (unsigned)(src + 1) * 256u);  // B(src)(t)
        float* ugp_n = ((t + 1) & 1) ? A.ugp2 : A.ugp;
        float* ucb_n = ((t + 1) & 1) ? A.ucb2 : A.ucb;
        stage_swz_coh(A.hst + (size_t)src * BB * HH, sx, tid);
        __syncthreads();
        for (int it = 0; lo + it * 4 < hi; ++it) {
          int u = lo + it * 4 + wid;
          if (u < hi) phaseA_unit(A, sx, scr, wid, lane, src, u, ugp_n, ucb_n);
        }
        arrive(g_cntA);
      } else {
        wait_for(g_cntB, 3u * TT * 256u);
      }
    }
  }
  // final states -> d_out tail (coherent reads; grid-stride)
  float* dst = A.out + (size_t)TT * BB * HH;
  for (size_t i = (size_t)blockIdx.x * 256 + threadIdx.x; i < 2 * SZ_ST;
       i += (size_t)gridDim.x * 256) {
    if (i < SZ_ST) dst[i] = cload(A.hst + i);
    else dst[i] = cload(A.cst + (i - SZ_ST));
  }
}

// ---------------- r15 kernel (fallback when workspace lacks the double buffer)
__global__ __launch_bounds__(256, 2) void k_persist_np(KArgs A) {
  __shared__ float sx[BB * HH];
  __shared__ float scr[2048];
  unsigned int tgt = 0;
  const unsigned int nb = gridDim.x;
  for (int t = 0; t < TT; ++t) {
    phaseA_work(A, sx, scr, A.ugp, A.ucb);
    tgt += nb;
    arrive(g_cntB);
    wait_for(g_cntB, tgt);
    for (int l = 0; l < 3; ++l) {
      tgt += 256;
      if (blockIdx.x < 256) {
        phaseB_work(A, sx, scr, l, t, A.ugp, A.ucb);
        arrive(g_cntB);
        wait_for(g_cntB, tgt);
      } else if (l == 2) {
        __syncthreads();
        wait_for(g_cntB, tgt);
      }
    }
  }
  float* dst = A.out + (size_t)TT * BB * HH;
  for (size_t i = (size_t)blockIdx.x * 256 + threadIdx.x; i < 2 * SZ_ST;
       i += (size_t)gridDim.x * 256) {
    if (i < SZ_ST) dst[i] = cload(A.hst + i);
    else dst[i] = cload(A.cst + (i - SZ_ST));
  }
}

// fallback wrappers (non-cooperative path)
__global__ __launch_bounds__(256, 2) void k_phaseA(KArgs A) {
  __shared__ float sx[BB * HH];
  __shared__ float scr[2048];
  phaseA_work(A, sx, scr, A.ugp, A.ucb);
}
__global__ __launch_bounds__(256, 2) void k_phaseB(KArgs A, int l, int t) {
  __shared__ float sx[BB * HH];
  __shared__ float scr[2048];
  phaseB_work(A, sx, scr, l, t, A.ugp, A.ucb);
}

extern "C" void kernel_launch(void* const* d_in, const int* in_sizes, int n_in,
                              void* d_out, int out_size, void* d_ws, size_t ws_size,
                              hipStream_t stream) {
  const float* x     = (const float*)d_in[0];
  const float* h0    = (const float*)d_in[1];
  const float* c0    = (const float*)d_in[2];
  const float* W_i2h = (const float*)d_in[3];
  const float* b_i2h = (const float*)d_in[4];
  const float* W_h2h = (const float*)d_in[5];
  const float* b_h2h = (const float*)d_in[6];
  const float* W_wc  = (const float*)d_in[7];
  const float* b_wc  = (const float*)d_in[8];
  const float* W_wg  = (const float*)d_in[9];
  const float* b_wg  = (const float*)d_in[10];
  const float* W_ug  = (const float*)d_in[11];
  const float* b_ug  = (const float*)d_in[12];
  const float* W_uc  = (const float*)d_in[13];
  const float* b_uc  = (const float*)d_in[14];
  float* out = (float*)d_out;
  float* ws  = (float*)d_ws;

  if (ws_size < WS_FLOATS * sizeof(float)) return;
  const bool pipe = ws_size >= WS_FLOATS2 * sizeof(float);

  float* i2hT = ws + OFF_I2HT;
  float* h2hT = ws + OFF_H2HT;
  float* wcT  = ws + OFF_WCT;
  float* wgT  = ws + OFF_WGT;
  float* ugT  = ws + OFF_UGT;
  float* ucT  = ws + OFF_UCT;
  float* hst  = ws + OFF_HST;
  float* cst  = ws + OFF_CST;
  float* gh   = ws + OFF_GH;
  float* ugp  = ws + OFF_UGP;
  float* ucb  = ws + OFF_UCB;

  dim3 b256(256);
  hipLaunchKernelGGL(k_transpose, dim3(48, 16, 3), b256, 0, stream, W_i2h, i2hT, 512, 1536);
  hipLaunchKernelGGL(k_transpose, dim3(48, 16, 3), b256, 0, stream, W_h2h, h2hT, 512, 1536);
  hipLaunchKernelGGL(k_transpose, dim3(16, 16, 3), b256, 0, stream, W_wc, wcT, 512, 512);
  hipLaunchKernelGGL(k_transpose, dim3(16, 16, 9), b256, 0, stream, W_wg, wgT, 512, 512);
  hipLaunchKernelGGL(k_transpose, dim3(16, 48, 9), b256, 0, stream, W_ug, ugT, 1536, 512);
  hipLaunchKernelGGL(k_transpose, dim3(16, 16, 9), b256, 0, stream, W_uc, ucT, 512, 512);
  hipLaunchKernelGGL(k_copy, dim3(192), b256, 0, stream, h0, hst, (int)SZ_ST);
  hipLaunchKernelGGL(k_copy, dim3(192), b256, 0, stream, c0, cst, (int)SZ_ST);
  hipLaunchKernelGGL(k_zero, dim3(1), dim3(256), 0, stream);

  KArgs ka;
  ka.x = x;
  ka.b_i2h = b_i2h; ka.b_h2h = b_h2h; ka.b_wg = b_wg; ka.b_ug = b_ug;
  ka.b_uc = b_uc; ka.b_wc = b_wc;
  ka.i2hT = i2hT; ka.h2hT = h2hT; ka.wcT = wcT; ka.wgT = wgT;
  ka.ugT = ugT; ka.ucT = ucT;
  ka.hst = hst; ka.cst = cst; ka.gh = gh; ka.ugp = ugp; ka.ucb = ucb;
  ka.ugp2 = pipe ? (ws + OFF_UGP2) : ugp;
  ka.ucb2 = pipe ? (ws + OFF_UCB2) : ucb;
  ka.out = out;

  void* params[1] = {&ka};
  hipError_t ce = hipLaunchCooperativeKernel(
      pipe ? (const void*)k_persist_pipe : (const void*)k_persist_np,
      dim3(480), dim3(256), params, 0, stream);
  if (ce != hipSuccess) {
    for (int t = 0; t < TT; ++t) {
      hipLaunchKernelGGL(k_phaseA, dim3(480), b256, 0, stream, ka);
      for (int l = 0; l < 3; ++l)
        hipLaunchKernelGGL(k_phaseB, dim3(256), b256, 0, stream, ka, l, t);
    }
    hipLaunchKernelGGL(k_copy, dim3(192), b256, 0, stream, hst,
                       out + (size_t)TT * BB * HH, (int)SZ_ST);
    hipLaunchKernelGGL(k_copy, dim3(192), b256, 0, stream, cst,
                       out + (size_t)TT * BB * HH + SZ_ST, (int)SZ_ST);
  }
}

// Round 17
// 16311.302 us; speedup vs baseline: 1.8672x; 1.8672x over previous
//
#include <hip/hip_runtime.h>
#include <math.h>

#define TT 256
#define BB 32
#define DD 512
#define HH 512
#define H3 1536

static constexpr size_t SZ_I2HT = 3ull * H3 * HH;
static constexpr size_t SZ_H2HT = 3ull * H3 * HH;
static constexpr size_t SZ_WCT  = 3ull * HH * HH;
static constexpr size_t SZ_WGT  = 9ull * HH * HH;
static constexpr size_t SZ_UGT  = 9ull * HH * H3;
static constexpr size_t SZ_UCT  = 9ull * HH * HH;
static constexpr size_t SZ_ST   = 3ull * BB * HH;
static constexpr size_t SZ_GH   = 3ull * BB * H3;
static constexpr size_t SZ_UGP  = 3ull * 9 * BB * HH;  // partials [chunk][q][b][col]
static constexpr size_t SZ_UCB  = 9ull * BB * HH;

static constexpr size_t OFF_I2HT = 0;
static constexpr size_t OFF_H2HT = OFF_I2HT + SZ_I2HT;
static constexpr size_t OFF_WCT  = OFF_H2HT + SZ_H2HT;
static constexpr size_t OFF_WGT  = OFF_WCT + SZ_WCT;
static constexpr size_t OFF_UGT  = OFF_WGT + SZ_WGT;
static constexpr size_t OFF_UCT  = OFF_UGT + SZ_UGT;
static constexpr size_t OFF_HST  = OFF_UCT + SZ_UCT;
static constexpr size_t OFF_CST  = OFF_HST + SZ_ST;
static constexpr size_t OFF_GH   = OFF_CST + SZ_ST;
static constexpr size_t OFF_UGP  = OFF_GH + SZ_GH;
static constexpr size_t OFF_UCB  = OFF_UGP + SZ_UGP;
static constexpr size_t WS_FLOATS = OFF_UCB + SZ_UCB;

struct KArgs {
  const float* x;
  const float *b_i2h, *b_h2h, *b_wg, *b_ug, *b_uc, *b_wc;
  const float *i2hT, *h2hT, *wcT, *wgT, *ugT, *ucT;
  float *hst, *cst, *gh, *ugp, *ucb, *out;
};

// ---------------- cross-XCD coherent access helpers (sc1 path, no cache flushes)
__device__ __forceinline__ float cload(const float* p) {
  return __hip_atomic_load(p, __ATOMIC_RELAXED, __HIP_MEMORY_SCOPE_AGENT);
}
__device__ __forceinline__ void cstore(float* p, float v) {
  __hip_atomic_store(p, v, __ATOMIC_RELAXED, __HIP_MEMORY_SCOPE_AGENT);
}
__device__ __forceinline__ void cstore2(float* p, float2 v) {
  __hip_atomic_store(reinterpret_cast<unsigned long long*>(p),
                     __builtin_bit_cast(unsigned long long, v),
                     __ATOMIC_RELAXED, __HIP_MEMORY_SCOPE_AGENT);
}

// ---------------- barrier: 64-sharded arrivals + wave-parallel poll (r13-validated)
// Split into arrive+wait (producers) and wait-only (pure consumers) — r15.
__device__ unsigned int g_cnt[64 * 64];   // counters at g_cnt[i*64], 256B apart

__global__ void k_zero() {
  for (int i = threadIdx.x; i < 64 * 64; i += blockDim.x) g_cnt[i] = 0u;
}

__device__ __forceinline__ void poll_until(unsigned int target) {
  if (threadIdx.x < 64) {
    for (;;) {
      unsigned int s = __hip_atomic_load(&g_cnt[threadIdx.x * 64],
                                         __ATOMIC_RELAXED, __HIP_MEMORY_SCOPE_AGENT);
      s += __shfl_xor(s, 1);
      s += __shfl_xor(s, 2);
      s += __shfl_xor(s, 4);
      s += __shfl_xor(s, 8);
      s += __shfl_xor(s, 16);
      s += __shfl_xor(s, 32);
      if (s >= target) break;
      __builtin_amdgcn_s_sleep(8);
    }
  }
}

__device__ __forceinline__ void gbar_arrive(unsigned int target) {
  __syncthreads();
  if (threadIdx.x == 0) {
    __hip_atomic_fetch_add(&g_cnt[(blockIdx.x & 63) * 64], 1u,
                           __ATOMIC_RELAXED, __HIP_MEMORY_SCOPE_AGENT);
  }
  poll_until(target);
  __syncthreads();
}

__device__ __forceinline__ void gbar_wait(unsigned int target) {
  __syncthreads();
  poll_until(target);
  __syncthreads();
}

// ---------------- transpose: in [K][N] -> out [N][K], grid (N/32, K/32, nmat)
__global__ __launch_bounds__(256) void k_transpose(const float* __restrict__ in,
                                                   float* __restrict__ out,
                                                   int K, int N) {
  __shared__ float t[32][33];
  size_t mo = (size_t)blockIdx.z * K * N;
  in += mo; out += mo;
  int n0 = blockIdx.x * 32, k0 = blockIdx.y * 32;
  int c = threadIdx.x & 31, r0 = (threadIdx.x >> 5) * 4;
#pragma unroll
  for (int i = 0; i < 4; ++i) t[r0 + i][c] = in[(size_t)(k0 + r0 + i) * N + n0 + c];
  __syncthreads();
#pragma unroll
  for (int i = 0; i < 4; ++i) out[(size_t)(n0 + r0 + i) * K + k0 + c] = t[c][r0 + i];
}

__global__ void k_copy(const float* __restrict__ a, float* __restrict__ o, int n) {
  int i = blockIdx.x * blockDim.x + threadIdx.x;
  if (i < n) o[i] = a[i];
}

// k-aware XOR swizzle: granule g (16B) of a row stored at slot g^((g>>4)&7).
__device__ __forceinline__ int xslot(int g) { return g ^ ((g >> 4) & 7); }

// 8-row x stage for phase B l==0 (16 KB; the unit only reads rows bq*8..bq*8+7)
__device__ __forceinline__ void stage_rows8(const float* __restrict__ src,
                                            float* __restrict__ sx, int tid, int row0) {
#pragma unroll
  for (int i = 0; i < 4; ++i) {
    int fi = tid + i * 256;           // 0..1023 over 8 rows x 128 granules
    int b = row0 + (fi >> 7), g = fi & 127;
    float4 v = reinterpret_cast<const float4*>(src)[(size_t)b * 128 + g];
    *reinterpret_cast<float4*>(&sx[b * HH + (xslot(g) << 2)]) = v;
  }
}

// 8-row coherent 16B sc1 stage for phase B l>0 (r14 staging pattern, 4 loads)
__device__ __forceinline__ void stage_rows8_coh(const float* __restrict__ src,
                                                float* __restrict__ sx, int tid, int row0) {
  float4 v[4];
#pragma unroll
  for (int i = 0; i < 4; ++i) {
    int fi = tid + i * 256;
    int b = row0 + (fi >> 7), g = fi & 127;
    const float* p = src + (size_t)b * HH + g * 4;
    asm volatile("global_load_dwordx4 %0, %1, off sc1" : "=v"(v[i]) : "v"(p));
  }
  asm volatile("s_waitcnt vmcnt(0)" ::: "memory");
#pragma unroll
  for (int i = 0; i < 4; ++i) {
    int fi = tid + i * 256;
    int b = row0 + (fi >> 7), g = fi & 127;
    *reinterpret_cast<float4*>(&sx[b * HH + (xslot(g) << 2)]) = v[i];
  }
}

// 16-row parity-half stage for phase A (32 KB; r14/r15-validated)
__device__ __forceinline__ void stage_half_coh(const float* __restrict__ src,
                                               float* __restrict__ sx, int tid) {
  float4 v[8];
#pragma unroll
  for (int i = 0; i < 8; ++i) {
    int fi = tid + i * 256;
    const float* p = src + (size_t)fi * 4;
    asm volatile("global_load_dwordx4 %0, %1, off sc1" : "=v"(v[i]) : "v"(p));
  }
  asm volatile("s_waitcnt vmcnt(0)" ::: "memory");
#pragma unroll
  for (int i = 0; i < 8; ++i) {
    int fi = tid + i * 256;
    int b = fi >> 7, g = fi & 127;
    *reinterpret_cast<float4*>(&sx[b * HH + (xslot(g) << 2)]) = v[i];
  }
}

__device__ __forceinline__ float dot4(float4 x, float4 w) {
  return x.x * w.x + x.y * w.y + x.z * w.z + x.w * w.w;
}

__device__ __forceinline__ float sigm(float x) { return 1.0f / (1.0f + expf(-x)); }

// ---------------- phase A: 1440 units of (32 cols x 16 b), 3 per block (waves 0-2)
// Parity partition (r14/r15-validated): all 3 units of a block share b-half p = blk&1.
__device__ __forceinline__ void phaseA_work(const KArgs& A, float* sx, float* scr) {
  const int tid = threadIdx.x;
  const int bid = blockIdx.x;
  const int src = bid / 160;
  const int blk = bid - src * 160;  // 0..159
  const int p = blk & 1;            // shared b-half for the block's 3 units
  stage_half_coh(A.hst + ((size_t)src * BB + p * 16) * HH, sx, tid);
  __syncthreads();
  const int wid = tid >> 6;
  if (wid == 3) return;  // 3 units per block; wave 3 idles
  const int lane = tid & 63;
  const int cq = lane & 7, kc = lane >> 3;
  const int u = (blk >> 1) * 6 + wid * 2 + p;  // 0..479 within src; u&1 == p

  const float* wb; size_t wstride; size_t koff = 0;
  float* op; int opstride;
  const float* bias1 = nullptr; const float* bias2 = nullptr;
  int col0;
  if (u < 96) {  // gh (h2h for layer src), cols in [0,1536)
    int w = u >> 1; col0 = w * 32;
    wb = A.h2hT + (size_t)src * H3 * HH; wstride = HH;
    op = A.gh + (size_t)src * BB * H3; opstride = H3;
    bias1 = A.b_i2h + src * H3; bias2 = A.b_h2h + src * H3;
  } else if (u < 384) {  // ugp partial, chunk = src, q in [0,9), cols in [0,512)
    int v = u - 96; int w = v >> 1;
    int q = w >> 4; col0 = (w & 15) * 32;
    wb = A.ugT + (size_t)q * HH * H3; wstride = H3; koff = (size_t)src * HH;
    op = A.ugp + (size_t)(src * 9 + q) * BB * HH; opstride = HH;
    if (src == 0) { bias1 = A.b_wg + q * HH; bias2 = A.b_ug + q * HH; }
  } else {  // ucb, q = qi*3 + src
    int v = u - 384; int w = v >> 1;
    int qi = w >> 4; int q = qi * 3 + src; col0 = (w & 15) * 32;
    wb = A.ucT + (size_t)q * HH * HH; wstride = HH;
    op = A.ucb + (size_t)q * BB * HH; opstride = HH;
    bias1 = A.b_uc + q * HH;
  }

  const int cbase = col0 + cq * 4;
  const float* w0 = wb + (size_t)(cbase + 0) * wstride + koff;
  const float* w1 = wb + (size_t)(cbase + 1) * wstride + koff;
  const float* w2 = wb + (size_t)(cbase + 2) * wstride + koff;
  const float* w3 = wb + (size_t)(cbase + 3) * wstride + koff;
  const float* xb = sx;  // staged half == this block's b-rows

  float acc[4][16];
#pragma unroll
  for (int c = 0; c < 4; ++c)
#pragma unroll
    for (int b = 0; b < 16; ++b) acc[c][b] = 0.f;

  for (int jt = 0; jt < 16; ++jt) {
    const int g = jt * 8 + kc;        // granule 0..127; 8 kc-lanes contiguous
    const int k = g << 2;
    float4 wv0 = *reinterpret_cast<const float4*>(w0 + k);
    float4 wv1 = *reinterpret_cast<const float4*>(w1 + k);
    float4 wv2 = *reinterpret_cast<const float4*>(w2 + k);
    float4 wv3 = *reinterpret_cast<const float4*>(w3 + k);
    const int so = xslot(g) << 2;
#pragma unroll
    for (int b = 0; b < 16; ++b) {
      float4 xv = *reinterpret_cast<const float4*>(&xb[b * HH + so]);
      acc[0][b] += dot4(xv, wv0);
      acc[1][b] += dot4(xv, wv1);
      acc[2][b] += dot4(xv, wv2);
      acc[3][b] += dot4(xv, wv3);
    }
  }

  // reduce across the 8 kc chunks (lane bits 3..5)
#pragma unroll
  for (int c = 0; c < 4; ++c)
#pragma unroll
    for (int b = 0; b < 16; ++b) {
      float v = acc[c][b];
      v += __shfl_xor(v, 8);
      v += __shfl_xor(v, 16);
      v += __shfl_xor(v, 32);
      acc[c][b] = v;
    }

  // per-wave LDS bounce so stores use compile-time register indices
  float* wscr = scr + wid * 512;  // [cq][c][b16] = 512 floats
  if (kc == 0) {
#pragma unroll
    for (int c = 0; c < 4; ++c) {
#pragma unroll
      for (int b = 0; b < 16; b += 4) {
        *reinterpret_cast<float4*>(&wscr[cq * 64 + c * 16 + b]) =
            make_float4(acc[c][b], acc[c][b + 1], acc[c][b + 2], acc[c][b + 3]);
      }
    }
  }
  // same-wave LDS write->read; vectorized 8B coherent stores
  {
    const int bl = lane & 15;     // local b
    const int cg = lane >> 4;     // 0..3 -> 8 cols each
    const int b = p * 16 + bl;
    float* orow = op + (size_t)b * opstride + col0 + cg * 8;
#pragma unroll
    for (int i = 0; i < 8; i += 2) {
      int cl0 = cg * 8 + i, cl1 = cl0 + 1;
      float v0 = wscr[(cl0 >> 2) * 64 + (cl0 & 3) * 16 + bl];
      float v1 = wscr[(cl1 >> 2) * 64 + (cl1 & 3) * 16 + bl];
      int col = col0 + cl0;
      if (bias1) { v0 += bias1[col]; v1 += bias1[col + 1]; }
      if (bias2) { v0 += bias2[col]; v1 += bias2[col + 1]; }
      cstore2(orow + i, make_float2(v0, v1));
    }
  }
}

// ---------------- phase B: 256 units of (8 j x 8 b), unit = bid (<256).
// r15-verbatim except staging: only the unit's 8 b-rows (16 KB, was 64 KB).
__device__ __forceinline__ void phaseB_work(const KArgs& A, float* sx, float* scr, int l, int t) {
  const int tid = threadIdx.x;
  const int bid = blockIdx.x;
  const int jg = (bid & 7) + ((bid >> 5) << 3);  // XCD-aware 4x weight dedup (r10)
  const int bq = (bid >> 3) & 3;
  if (l == 0) stage_rows8(A.x + (size_t)t * BB * DD, sx, tid, bq * 8);
  else        stage_rows8_coh(A.hst + (size_t)(l - 1) * BB * HH, sx, tid, bq * 8);
  __syncthreads();
  const int jq = tid & 7;
  const int kcl = (tid >> 3) & 7;
  const int wid = tid >> 6;
  const int j0 = jg * 8;
  const int j = j0 + jq;
  const float* w0 = A.i2hT + ((size_t)l * H3 + j) * HH;
  const float* w1 = A.i2hT + ((size_t)l * H3 + HH + j) * HH;
  const float* w2 = A.i2hT + ((size_t)l * H3 + 2 * HH + j) * HH;
  const float* w3 = A.wgT + ((size_t)(l * 3 + 0) * HH + j) * HH;
  const float* w4 = A.wgT + ((size_t)(l * 3 + 1) * HH + j) * HH;
  const float* w5 = A.wgT + ((size_t)(l * 3 + 2) * HH + j) * HH;
  const float* w6 = A.wcT + ((size_t)l * HH + j) * HH;
  const float* xb = sx + (size_t)(bq * 8) * HH;

  float acc[7][8];
#pragma unroll
  for (int m = 0; m < 7; ++m)
#pragma unroll
    for (int b = 0; b < 8; ++b) acc[m][b] = 0.f;

  for (int jt = 0; jt < 4; ++jt) {
    const int g = wid * 32 + jt * 8 + kcl;
    const int k = g << 2;
    float4 v0 = *reinterpret_cast<const float4*>(w0 + k);
    float4 v1 = *reinterpret_cast<const float4*>(w1 + k);
    float4 v2 = *reinterpret_cast<const float4*>(w2 + k);
    float4 v3 = *reinterpret_cast<const float4*>(w3 + k);
    float4 v4 = *reinterpret_cast<const float4*>(w4 + k);
    float4 v5 = *reinterpret_cast<const float4*>(w5 + k);
    float4 v6 = *reinterpret_cast<const float4*>(w6 + k);
    const int so = xslot(g) << 2;
#pragma unroll
    for (int b = 0; b < 8; ++b) {
      float4 xv = *reinterpret_cast<const float4*>(&xb[b * HH + so]);
      acc[0][b] += dot4(xv, v0);
      acc[1][b] += dot4(xv, v1);
      acc[2][b] += dot4(xv, v2);
      acc[3][b] += dot4(xv, v3);
      acc[4][b] += dot4(xv, v4);
      acc[5][b] += dot4(xv, v5);
      acc[6][b] += dot4(xv, v6);
    }
  }
#pragma unroll
  for (int m = 0; m < 7; ++m)
#pragma unroll
    for (int b = 0; b < 8; ++b) {
      float v = acc[m][b];
      v += __shfl_xor(v, 8);
      v += __shfl_xor(v, 16);
      v += __shfl_xor(v, 32);
      acc[m][b] = v;
    }
  if ((tid & 63) < 8) {
    float* pp = scr + wid * 448 + jq * 56;
#pragma unroll
    for (int m = 0; m < 7; ++m) {
      *reinterpret_cast<float4*>(&pp[m * 8 + 0]) =
          make_float4(acc[m][0], acc[m][1], acc[m][2], acc[m][3]);
      *reinterpret_cast<float4*>(&pp[m * 8 + 4]) =
          make_float4(acc[m][4], acc[m][5], acc[m][6], acc[m][7]);
    }
  }
  __syncthreads();
  if (tid < 64) {
    const int jr = tid & 7, br = tid >> 3;
    float a[7];
#pragma unroll
    for (int m = 0; m < 7; ++m) {
      const int o = jr * 56 + m * 8 + br;
      a[m] = scr[o] + scr[448 + o] + scr[896 + o] + scr[1344 + o];
    }
    const int jj = j0 + jr;
    const int b = bq * 8 + br;
    const size_t bh_ = (size_t)b * HH + jj;
    const float* gh_l = A.gh + (size_t)l * BB * H3;
    float si = sigm(a[0] + cload(&gh_l[(size_t)b * H3 + jj]));
    float sf = sigm(a[1] + cload(&gh_l[(size_t)b * H3 + HH + jj]));
    float so = sigm(a[2] + cload(&gh_l[(size_t)b * H3 + 2 * HH + jj]));
    const size_t CH = 9ull * BB * HH;
    size_t o0 = ((size_t)(l * 3 + 0) * BB + b) * HH + jj;
    size_t o1 = ((size_t)(l * 3 + 1) * BB + b) * HH + jj;
    size_t o2 = ((size_t)(l * 3 + 2) * BB + b) * HH + jj;
    float g0 = sigm(a[3] + cload(&A.ugp[o0]) + cload(&A.ugp[o0 + CH]) + cload(&A.ugp[o0 + 2 * CH]));
    float g1 = sigm(a[4] + cload(&A.ugp[o1]) + cload(&A.ugp[o1 + CH]) + cload(&A.ugp[o1 + 2 * CH]));
    float g2 = sigm(a[5] + cload(&A.ugp[o2]) + cload(&A.ugp[o2 + CH]) + cload(&A.ugp[o2 + 2 * CH]));
    float accc = a[6] + A.b_wc[l * HH + jj]
               + g0 * cload(&A.ucb[o0]) + g1 * cload(&A.ucb[o1]) + g2 * cload(&A.ucb[o2]);
    float cand = tanhf(accc);
    float* cp = A.cst + (size_t)l * BB * HH + bh_;
    float* hp = A.hst + (size_t)l * BB * HH + bh_;
    float cn = sf * cload(cp) + si * cand;
    float hn = so * tanhf(cn);
    cstore(cp, cn);
    cstore(hp, hn);
    if (l == 2) A.out[(size_t)t * BB * HH + bh_] = hn;
  }
}

// ---------------- persistent cooperative kernel: whole sequence, grid 480
// Phase-specific barrier participation (r15): A-barrier 480 arrivals; B-phase
// barriers 256; idle blocks skip B0/B1 and poll only the cumulative B2 target.
__global__ __launch_bounds__(256, 2) void k_persist(KArgs A) {
  __shared__ float sx[BB * HH];
  __shared__ float scr[2048];
  unsigned int tgt = 0;
  const unsigned int nb = gridDim.x;   // 480
  for (int t = 0; t < TT; ++t) {
    phaseA_work(A, sx, scr);
    tgt += nb;
    gbar_arrive(tgt);
    for (int l = 0; l < 3; ++l) {
      tgt += 256;
      if (blockIdx.x < 256) {
        phaseB_work(A, sx, scr, l, t);
        gbar_arrive(tgt);
      } else if (l == 2) {
        gbar_wait(tgt);
      }
    }
  }
  // final states -> d_out tail (coherent reads; grid-stride)
  float* dst = A.out + (size_t)TT * BB * HH;
  for (size_t i = (size_t)blockIdx.x * 256 + threadIdx.x; i < 2 * SZ_ST;
       i += (size_t)gridDim.x * 256) {
    if (i < SZ_ST) dst[i] = cload(A.hst + i);
    else dst[i] = cload(A.cst + (i - SZ_ST));
  }
}

// fallback wrappers (non-cooperative path)
__global__ __launch_bounds__(256, 2) void k_phaseA(KArgs A) {
  __shared__ float sx[BB * HH];
  __shared__ float scr[2048];
  phaseA_work(A, sx, scr);
}
__global__ __launch_bounds__(256, 2) void k_phaseB(KArgs A, int l, int t) {
  __shared__ float sx[BB * HH];
  __shared__ float scr[2048];
  phaseB_work(A, sx, scr, l, t);
}

extern "C" void kernel_launch(void* const* d_in, const int* in_sizes, int n_in,
                              void* d_out, int out_size, void* d_ws, size_t ws_size,
                              hipStream_t stream) {
  const float* x     = (const float*)d_in[0];
  const float* h0    = (const float*)d_in[1];
  const float* c0    = (const float*)d_in[2];
  const float* W_i2h = (const float*)d_in[3];
  const float* b_i2h = (const float*)d_in[4];
  const float* W_h2h = (const float*)d_in[5];
  const float* b_h2h = (const float*)d_in[6];
  const float* W_wc  = (const float*)d_in[7];
  const float* b_wc  = (const float*)d_in[8];
  const float* W_wg  = (const float*)d_in[9];
  const float* b_wg  = (const float*)d_in[10];
  const float* W_ug  = (const float*)d_in[11];
  const float* b_ug  = (const float*)d_in[12];
  const float* W_uc  = (const float*)d_in[13];
  const float* b_uc  = (const float*)d_in[14];
  float* out = (float*)d_out;
  float* ws  = (float*)d_ws;

  if (ws_size < WS_FLOATS * sizeof(float)) return;  // need ~72.6 MB scratch

  float* i2hT = ws + OFF_I2HT;
  float* h2hT = ws + OFF_H2HT;
  float* wcT  = ws + OFF_WCT;
  float* wgT  = ws + OFF_WGT;
  float* ugT  = ws + OFF_UGT;
  float* ucT  = ws + OFF_UCT;
  float* hst  = ws + OFF_HST;
  float* cst  = ws + OFF_CST;
  float* gh   = ws + OFF_GH;
  float* ugp  = ws + OFF_UGP;
  float* ucb  = ws + OFF_UCB;

  dim3 b256(256);
  hipLaunchKernelGGL(k_transpose, dim3(48, 16, 3), b256, 0, stream, W_i2h, i2hT, 512, 1536);
  hipLaunchKernelGGL(k_transpose, dim3(48, 16, 3), b256, 0, stream, W_h2h, h2hT, 512, 1536);
  hipLaunchKernelGGL(k_transpose, dim3(16, 16, 3), b256, 0, stream, W_wc, wcT, 512, 512);
  hipLaunchKernelGGL(k_transpose, dim3(16, 16, 9), b256, 0, stream, W_wg, wgT, 512, 512);
  hipLaunchKernelGGL(k_transpose, dim3(16, 48, 9), b256, 0, stream, W_ug, ugT, 1536, 512);
  hipLaunchKernelGGL(k_transpose, dim3(16, 16, 9), b256, 0, stream, W_uc, ucT, 512, 512);
  hipLaunchKernelGGL(k_copy, dim3(192), b256, 0, stream, h0, hst, (int)SZ_ST);
  hipLaunchKernelGGL(k_copy, dim3(192), b256, 0, stream, c0, cst, (int)SZ_ST);
  hipLaunchKernelGGL(k_zero, dim3(1), dim3(256), 0, stream);

  KArgs ka;
  ka.x = x;
  ka.b_i2h = b_i2h; ka.b_h2h = b_h2h; ka.b_wg = b_wg; ka.b_ug = b_ug;
  ka.b_uc = b_uc; ka.b_wc = b_wc;
  ka.i2hT = i2hT; ka.h2hT = h2hT; ka.wcT = wcT; ka.wgT = wgT;
  ka.ugT = ugT; ka.ucT = ucT;
  ka.hst = hst; ka.cst = cst; ka.gh = gh; ka.ugp = ugp; ka.ucb = ucb;
  ka.out = out;

  void* params[1] = {&ka};
  hipError_t ce = hipLaunchCooperativeKernel((const void*)k_persist, dim3(480), dim3(256),
                                             params, 0, stream);
  if (ce != hipSuccess) {
    for (int t = 0; t < TT; ++t) {
      hipLaunchKernelGGL(k_phaseA, dim3(480), b256, 0, stream, ka);
      for (int l = 0; l < 3; ++l)
        hipLaunchKernelGGL(k_phaseB, dim3(256), b256, 0, stream, ka, l, t);
    }
    hipLaunchKernelGGL(k_copy, dim3(192), b256, 0, stream, hst,
                       out + (size_t)TT * BB * HH, (int)SZ_ST);
    hipLaunchKernelGGL(k_copy, dim3(192), b256, 0, stream, cst,
                       out + (size_t)TT * BB * HH + SZ_ST, (int)SZ_ST);
  }
}